// Round 2
// baseline (199.427 us; speedup 1.0000x reference)
//
#include <hip/hip_runtime.h>

// Problem constants (match reference file)
constexpr int Dv = 160, Hv = 192, Wv = 160;
constexpr int NN = Dv * Hv * Wv;  // 4,915,200 voxels
constexpr int N4 = NN / 4;        // 4 voxels per thread (W % 4 == 0 -> never crosses a row)

// Branchless trilinear sample, 1 channel, padding='zeros', align_corners=False.
// Input coords already unnormalized to voxel space (ix along W, iy along H, iz along D).
// OOB handled by zeroing per-axis weights + clamping addresses (8 unconditional loads).
__device__ __forceinline__ float tri1(const float* __restrict__ v,
                                      float ix, float iy, float iz) {
  float fx = floorf(ix), fy = floorf(iy), fz = floorf(iz);
  float wx = ix - fx, wy = iy - fy, wz = iz - fz;
  int x0 = (int)fx, y0 = (int)fy, z0 = (int)fz;
  int x1 = x0 + 1, y1 = y0 + 1, z1 = z0 + 1;
  float wx0 = ((unsigned)x0 < (unsigned)Wv) ? (1.0f - wx) : 0.0f;
  float wx1 = ((unsigned)x1 < (unsigned)Wv) ? wx : 0.0f;
  float wy0 = ((unsigned)y0 < (unsigned)Hv) ? (1.0f - wy) : 0.0f;
  float wy1 = ((unsigned)y1 < (unsigned)Hv) ? wy : 0.0f;
  float wz0 = ((unsigned)z0 < (unsigned)Dv) ? (1.0f - wz) : 0.0f;
  float wz1 = ((unsigned)z1 < (unsigned)Dv) ? wz : 0.0f;
  int xa0 = min(max(x0, 0), Wv - 1), xa1 = min(max(x1, 0), Wv - 1);
  int ya0 = min(max(y0, 0), Hv - 1), ya1 = min(max(y1, 0), Hv - 1);
  int za0 = min(max(z0, 0), Dv - 1), za1 = min(max(z1, 0), Dv - 1);
  int r00 = (za0 * Hv + ya0) * Wv;
  int r01 = (za0 * Hv + ya1) * Wv;
  int r10 = (za1 * Hv + ya0) * Wv;
  int r11 = (za1 * Hv + ya1) * Wv;
  float v000 = v[r00 + xa0], v001 = v[r00 + xa1];
  float v010 = v[r01 + xa0], v011 = v[r01 + xa1];
  float v100 = v[r10 + xa0], v101 = v[r10 + xa1];
  float v110 = v[r11 + xa0], v111 = v[r11 + xa1];
  float c00 = v000 * wx0 + v001 * wx1;
  float c01 = v010 * wx0 + v011 * wx1;
  float c10 = v100 * wx0 + v101 * wx1;
  float c11 = v110 * wx0 + v111 * wx1;
  float c0 = c00 * wy0 + c01 * wy1;
  float c1 = c10 * wy0 + c11 * wy1;
  return c0 * wz0 + c1 * wz1;
}

// Trilinear sample of 3-channel flow1 at UNNORMALIZED-then-renormalized coords
// (the reference quirk): in-bounds only within a ~2x2x2 voxel corner, so the
// early-out branch is execz-taken for essentially every wave.
__device__ __forceinline__ void tri3_rare(const float* __restrict__ v,
                                          float gx, float gy, float gz,
                                          float& o0, float& o1, float& o2) {
  o0 = 0.0f; o1 = 0.0f; o2 = 0.0f;
  float ix = ((gx + 1.0f) * (float)Wv - 1.0f) * 0.5f;
  float iy = ((gy + 1.0f) * (float)Hv - 1.0f) * 0.5f;
  float iz = ((gz + 1.0f) * (float)Dv - 1.0f) * 0.5f;
  float fx = floorf(ix), fy = floorf(iy), fz = floorf(iz);
  int x0 = (int)fx, y0 = (int)fy, z0 = (int)fz;
  if (x0 < -1 || x0 >= Wv || y0 < -1 || y0 >= Hv || z0 < -1 || z0 >= Dv)
    return;  // entire 2x2x2 support out of bounds -> zeros
  float wx = ix - fx, wy = iy - fy, wz = iz - fz;
#pragma unroll
  for (int c = 0; c < 8; ++c) {
    const int dz = (c >> 2) & 1, dy = (c >> 1) & 1, dx = c & 1;
    int zi = z0 + dz, yi = y0 + dy, xi = x0 + dx;
    if ((unsigned)zi < (unsigned)Dv && (unsigned)yi < (unsigned)Hv &&
        (unsigned)xi < (unsigned)Wv) {
      float wgt = (dz ? wz : 1.0f - wz) * (dy ? wy : 1.0f - wy) *
                  (dx ? wx : 1.0f - wx);
      int lin = (zi * Hv + yi) * Wv + xi;
      o0 += wgt * v[lin];
      o1 += wgt * v[NN + lin];
      o2 += wgt * v[2 * NN + lin];
    }
  }
}

__global__ __launch_bounds__(256)
void st_fused4_kernel(const float* __restrict__ src,
                      const float* __restrict__ flow1,
                      const float* __restrict__ flow2,
                      const float* __restrict__ rfp,
                      float* __restrict__ out) {
  int t4 = blockIdx.x * blockDim.x + threadIdx.x;
  if (t4 >= N4) return;
  const float rf = rfp[0];

  int idx = t4 << 2;  // first of 4 consecutive voxels, same (d,h) row
  int w0 = idx % Wv;
  int tt = idx / Wv;
  int h = tt % Hv;
  int d = tt / Hv;

  // flow2 channels (d,h,w), each float4-coalesced
  float4 f2d = *(const float4*)(flow2 + idx);
  float4 f2h = *(const float4*)(flow2 + NN + idx);
  float4 f2w = *(const float4*)(flow2 + 2 * NN + idx);

  float f20[4] = {f2d.x, f2d.y, f2d.z, f2d.w};
  float f21[4] = {f2h.x, f2h.y, f2h.z, f2h.w};
  float f22[4] = {f2w.x, f2w.y, f2w.z, f2w.w};

  float of0[4], of1[4], of2[4], img[4];

#pragma unroll
  for (int j = 0; j < 4; ++j) {
    float wj = (float)(w0 + j);
    // grid2 (x,y,z) = (w + rf*f2_w, h + rf*f2_h, d + rf*f2_d)  [NOT normalized]
    float gx = wj + rf * f22[j];
    float gy = (float)h + rf * f21[j];
    float gz = (float)d + rf * f20[j];

    float a0, a1, a2;  // flow1 warped, channel order (d,h,w)
    tri3_rare(flow1, gx, gy, gz, a0, a1, a2);

    of0[j] = a0 + f20[j];
    of1[j] = a1 + f21[j];
    of2[j] = a2 + f22[j];

    // new_locs_total channels (d,h,w), denom (D-1,H-1,W-1); then to_xyz
    float nld = 2.0f * (((float)d + of0[j] * rf) / (float)(Dv - 1) - 0.5f);
    float nlh = 2.0f * (((float)h + of1[j] * rf) / (float)(Hv - 1) - 0.5f);
    float nlw = 2.0f * ((wj + of2[j] * rf) / (float)(Wv - 1) - 0.5f);

    // unnormalize (align_corners=False): ix=((x+1)*W-1)/2 etc.
    float ix = ((nlw + 1.0f) * (float)Wv - 1.0f) * 0.5f;
    float iy = ((nlh + 1.0f) * (float)Hv - 1.0f) * 0.5f;
    float iz = ((nld + 1.0f) * (float)Dv - 1.0f) * 0.5f;
    img[j] = tri1(src, ix, iy, iz);
  }

  // coalesced float4 stores: deform_2_img then the 3 out_flow channels
  *(float4*)(out + idx)          = make_float4(img[0], img[1], img[2], img[3]);
  *(float4*)(out + NN + idx)     = make_float4(of0[0], of0[1], of0[2], of0[3]);
  *(float4*)(out + 2 * NN + idx) = make_float4(of1[0], of1[1], of1[2], of1[3]);
  *(float4*)(out + 3 * NN + idx) = make_float4(of2[0], of2[1], of2[2], of2[3]);
}

extern "C" void kernel_launch(void* const* d_in, const int* in_sizes, int n_in,
                              void* d_out, int out_size, void* d_ws, size_t ws_size,
                              hipStream_t stream) {
  const float* src   = (const float*)d_in[0];
  const float* flow1 = (const float*)d_in[1];
  const float* flow2 = (const float*)d_in[2];
  const float* rfp   = (const float*)d_in[3];
  float* out = (float*)d_out;

  const int threads = 256;
  const int blocks = (N4 + threads - 1) / threads;
  hipLaunchKernelGGL(st_fused4_kernel, dim3(blocks), dim3(threads), 0, stream,
                     src, flow1, flow2, rfp, out);
}

// Round 3
// 185.415 us; speedup vs baseline: 1.0756x; 1.0756x over previous
//
#include <hip/hip_runtime.h>

// Problem constants (match reference file)
constexpr int Dv = 160, Hv = 192, Wv = 160;
constexpr int NN = Dv * Hv * Wv;  // 4,915,200 voxels

// Voxel tile per block (grid = 5 x 24 x 20 = 2400 blocks, 256 threads)
constexpr int TW = 32, TH = 8, TD = 8;
// Support tile: halo [-3, +4] per axis (|delta| <= ~2.9 interior)
constexpr int SX = TW + 7, SY = TH + 7, SZ = TD + 7;  // 39 x 15 x 15
constexpr int SLEN = SX * SY * SZ;                    // 8775
constexpr int SITER = (SLEN + 255) / 256;             // 35
constexpr int SPAD = SITER * 256;                     // 8960 floats = 35.84 KB

// Trilinear sample of 3-channel flow1 at quirk-unnormalized coords:
// in-bounds only near the (0,0,0) corner, so this is execz-skipped for
// essentially every wave.
__device__ __forceinline__ void tri3_rare(const float* __restrict__ v,
                                          float gx, float gy, float gz,
                                          float& o0, float& o1, float& o2) {
  o0 = 0.0f; o1 = 0.0f; o2 = 0.0f;
  float ix = ((gx + 1.0f) * (float)Wv - 1.0f) * 0.5f;
  float iy = ((gy + 1.0f) * (float)Hv - 1.0f) * 0.5f;
  float iz = ((gz + 1.0f) * (float)Dv - 1.0f) * 0.5f;
  float fx = floorf(ix), fy = floorf(iy), fz = floorf(iz);
  int x0 = (int)fx, y0 = (int)fy, z0 = (int)fz;
  if (x0 < -1 || x0 >= Wv || y0 < -1 || y0 >= Hv || z0 < -1 || z0 >= Dv)
    return;  // entire 2x2x2 support OOB -> zeros
  float wx = ix - fx, wy = iy - fy, wz = iz - fz;
#pragma unroll
  for (int c = 0; c < 8; ++c) {
    const int dz = (c >> 2) & 1, dy = (c >> 1) & 1, dx = c & 1;
    int zi = z0 + dz, yi = y0 + dy, xi = x0 + dx;
    if ((unsigned)zi < (unsigned)Dv && (unsigned)yi < (unsigned)Hv &&
        (unsigned)xi < (unsigned)Wv) {
      float wgt = (dz ? wz : 1.0f - wz) * (dy ? wy : 1.0f - wy) *
                  (dx ? wx : 1.0f - wx);
      int lin = (zi * Hv + yi) * Wv + xi;
      o0 += wgt * v[lin];
      o1 += wgt * v[NN + lin];
      o2 += wgt * v[2 * NN + lin];
    }
  }
}

__global__ __launch_bounds__(256)
void st_tiled_kernel(const float* __restrict__ src,
                     const float* __restrict__ flow1,
                     const float* __restrict__ flow2,
                     const float* __restrict__ rfp,
                     float* __restrict__ out) {
  __shared__ float tile[SPAD];

  const int tid = threadIdx.x;
  const int bx0 = blockIdx.x * TW;   // w origin
  const int by0 = blockIdx.y * TH;   // h origin
  const int bz0 = blockIdx.z * TD;   // d origin
  const float rf = rfp[0];

  const int lw = tid & (TW - 1);     // 0..31
  const int lh = tid >> 5;           // 0..7
  const int w = bx0 + lw;
  const int h = by0 + lh;

  // ---- issue flow2 prefetch for all 8 d-slices (coalesced, 24 loads) ----
  float f2d[TD], f2h[TD], f2w[TD];
#pragma unroll
  for (int ld = 0; ld < TD; ++ld) {
    int idx = ((bz0 + ld) * Hv + h) * Wv + w;
    f2d[ld] = flow2[idx];
    f2h[ld] = flow2[NN + idx];
    f2w[ld] = flow2[2 * NN + idx];
  }

  // ---- async global->LDS stage of the src support tile ----
  const int bxo = bx0 - 3, byo = by0 - 3, bzo = bz0 - 3;
#pragma unroll
  for (int i = 0; i < SITER; ++i) {
    int t = tid + i * 256;
    int tt = min(t, SLEN - 1);          // pad lanes duplicate last element
    int tz = tt / (SY * SX);
    int r = tt - tz * (SY * SX);
    int ty = r / SX;
    int tx = r - ty * SX;
    int gx = min(max(bxo + tx, 0), Wv - 1);
    int gy = min(max(byo + ty, 0), Hv - 1);
    int gz = min(max(bzo + tz, 0), Dv - 1);
    int g = (gz * Hv + gy) * Wv + gx;
    __builtin_amdgcn_global_load_lds(
        (const __attribute__((address_space(1))) void*)(src + g),
        (__attribute__((address_space(3))) void*)(tile + t), 4, 0, 0);
  }
  __syncthreads();  // drains vmcnt for the LDS stage

  const float wf = (float)w, hf = (float)h;
  constexpr float KX = (float)Wv / (float)(Wv - 1);
  constexpr float KY = (float)Hv / (float)(Hv - 1);
  constexpr float KZ = (float)Dv / (float)(Dv - 1);

#pragma unroll
  for (int ld = 0; ld < TD; ++ld) {
    const int d = bz0 + ld;
    const float df = (float)d;
    const int idx = (d * Hv + h) * Wv + w;

    // grid2 (x,y,z) = (w + rf*f2w, h + rf*f2h, d + rf*f2d)  [NOT normalized]
    float a0, a1, a2;  // flow1 warped (d,h,w channels)
    tri3_rare(flow1, wf + rf * f2w[ld], hf + rf * f2h[ld], df + rf * f2d[ld],
              a0, a1, a2);

    float of_d = a0 + f2d[ld];
    float of_h = a1 + f2h[ld];
    float of_w = a2 + f2w[ld];

    out[NN + idx] = of_d;
    out[2 * NN + idx] = of_h;
    out[3 * NN + idx] = of_w;

    // src sample coords (algebraically simplified, align_corners=False):
    // ix = (w + rf*of_w) * W/(W-1) - 0.5, etc.
    float ix = (wf + rf * of_w) * KX - 0.5f;
    float iy = (hf + rf * of_h) * KY - 0.5f;
    float iz = (df + rf * of_d) * KZ - 0.5f;

    float fx = floorf(ix), fy = floorf(iy), fz = floorf(iz);
    float wx = ix - fx, wy = iy - fy, wz = iz - fz;
    int x0 = (int)fx, y0 = (int)fy, z0 = (int)fz;

    // zeros-padding validity -> per-axis weights
    float wx0 = ((unsigned)x0 < (unsigned)Wv) ? (1.0f - wx) : 0.0f;
    float wx1 = ((unsigned)(x0 + 1) < (unsigned)Wv) ? wx : 0.0f;
    float wy0 = ((unsigned)y0 < (unsigned)Hv) ? (1.0f - wy) : 0.0f;
    float wy1 = ((unsigned)(y0 + 1) < (unsigned)Hv) ? wy : 0.0f;
    float wz0 = ((unsigned)z0 < (unsigned)Dv) ? (1.0f - wz) : 0.0f;
    float wz1 = ((unsigned)(z0 + 1) < (unsigned)Dv) ? wz : 0.0f;

    int tx = x0 - bxo, ty = y0 - byo, tz = z0 - bzo;
    bool fast = ((unsigned)tx <= (unsigned)(SX - 2)) &
                ((unsigned)ty <= (unsigned)(SY - 2)) &
                ((unsigned)tz <= (unsigned)(SZ - 2));

    float v000, v001, v010, v011, v100, v101, v110, v111;
    if (fast) {
      int base = (tz * SY + ty) * SX + tx;
      v000 = tile[base];
      v001 = tile[base + 1];
      v010 = tile[base + SX];
      v011 = tile[base + SX + 1];
      v100 = tile[base + SY * SX];
      v101 = tile[base + SY * SX + 1];
      v110 = tile[base + SY * SX + SX];
      v111 = tile[base + SY * SX + SX + 1];
    } else {
      // rare: out-of-tile (flow1-corner region) -> clamped global gather
      int xa0 = min(max(x0, 0), Wv - 1), xa1 = min(max(x0 + 1, 0), Wv - 1);
      int ya0 = min(max(y0, 0), Hv - 1), ya1 = min(max(y0 + 1, 0), Hv - 1);
      int za0 = min(max(z0, 0), Dv - 1), za1 = min(max(z0 + 1, 0), Dv - 1);
      int r00 = (za0 * Hv + ya0) * Wv;
      int r01 = (za0 * Hv + ya1) * Wv;
      int r10 = (za1 * Hv + ya0) * Wv;
      int r11 = (za1 * Hv + ya1) * Wv;
      v000 = src[r00 + xa0]; v001 = src[r00 + xa1];
      v010 = src[r01 + xa0]; v011 = src[r01 + xa1];
      v100 = src[r10 + xa0]; v101 = src[r10 + xa1];
      v110 = src[r11 + xa0]; v111 = src[r11 + xa1];
    }

    float c00 = v000 * wx0 + v001 * wx1;
    float c01 = v010 * wx0 + v011 * wx1;
    float c10 = v100 * wx0 + v101 * wx1;
    float c11 = v110 * wx0 + v111 * wx1;
    float c0 = c00 * wy0 + c01 * wy1;
    float c1 = c10 * wy0 + c11 * wy1;
    out[idx] = c0 * wz0 + c1 * wz1;
  }
}

extern "C" void kernel_launch(void* const* d_in, const int* in_sizes, int n_in,
                              void* d_out, int out_size, void* d_ws, size_t ws_size,
                              hipStream_t stream) {
  const float* src   = (const float*)d_in[0];
  const float* flow1 = (const float*)d_in[1];
  const float* flow2 = (const float*)d_in[2];
  const float* rfp   = (const float*)d_in[3];
  float* out = (float*)d_out;

  dim3 grid(Wv / TW, Hv / TH, Dv / TD);  // 5 x 24 x 20
  hipLaunchKernelGGL(st_tiled_kernel, grid, dim3(256), 0, stream,
                     src, flow1, flow2, rfp, out);
}